// Round 16
// baseline (882.129 us; speedup 1.0000x reference)
//
#include <hip/hip_runtime.h>
#include <hip/hip_bf16.h>

static constexpr int Bn = 32;
static constexpr int Hin = 256, Win = 256;
static constexpr int C1 = 64, H1 = 128, W1 = 128;
static constexpr int C2 = 32, H2 = 64, W2 = 64;
static constexpr int Dd = 64;    // latent dim
static constexpr int Kc = 512;   // codebook entries
static constexpr int ROWS = Bn * H2 * W2;  // 131072

// ws layout (floats): lossA(64) | idx | pk | z2 | k2a | k2b | T1 | G | wT2 | chunk
static constexpr int K2A_FLOATS = 64 * 32 * 36;   // 73728
static constexpr int K2B_FLOATS = 3 * 64 * 36;    // 6912 (k2t layout)
static constexpr int T1_FLOATS  = Kc * C2;        // 16384
static constexpr int G_FLOATS   = Kc * 9 * 64 * 4; // 1,179,648
static constexpr int WT2_FLOATS = 2 * 9 * 64 * 16; // 18432
static constexpr int FIX_FLOATS = 64 + ROWS + 2 * ROWS + ROWS + K2A_FLOATS +
                                  K2B_FLOATS + T1_FLOATS + G_FLOATS + 64 +
                                  WT2_FLOATS;
static constexpr int H1_PER_N = C1 * H1 * W1;    // 1,048,576
static constexpr int Z_PER_N  = H2 * W2 * Dd;    // 262,144
static constexpr int H2_PER_N = C2 * H2 * W2;    // 131,072

// ---------- fused setup: init | wtrans(dec_w2) | wtransq(dec_w3) | wt2 | gtab1 ----------
// All-independent writes (no inter-piece ordering), so fusion is safe.
// (Round-15 lesson: k_upg->k_border_a DO have an ordering dependency --
// the ring is overwritten -- so those must stay separate dispatches.)
__device__ __forceinline__ void dev_wtrans_one(
    const float* __restrict__ w, float* __restrict__ k2, int i)
{
  float W[3][3];
#pragma unroll
  for (int ty = 0; ty < 3; ++ty)
#pragma unroll
    for (int tx = 0; tx < 3; ++tx) W[ty][tx] = w[i * 9 + ty * 3 + tx];
  const float A[2][3][3] = {
      {{.75f, .25f, 0.f}, {.25f, .75f, 0.f}, {0.f, .75f, .25f}},
      {{.25f, .75f, 0.f}, {0.f, .75f, .25f}, {0.f, .25f, .75f}}};
#pragma unroll
  for (int py = 0; py < 2; ++py)
#pragma unroll
    for (int px = 0; px < 2; ++px)
#pragma unroll
      for (int a = 0; a < 3; ++a)
#pragma unroll
        for (int b = 0; b < 3; ++b) {
          float v = 0.f;
#pragma unroll
          for (int ty = 0; ty < 3; ++ty)
#pragma unroll
            for (int tx = 0; tx < 3; ++tx)
              v += W[ty][tx] * A[py][ty][a] * A[px][tx][b];
          k2[(size_t)i * 36 + (py * 2 + px) * 9 + a * 3 + b] = v;
        }
}

__global__ __launch_bounds__(256) void k_setup(
    float* __restrict__ lossA, unsigned long long* __restrict__ pk,
    const float* __restrict__ dec_w2, float* __restrict__ k2a,
    const float* __restrict__ dec_w3, float* __restrict__ k2t,
    const float* __restrict__ enc_w2, float* __restrict__ wT,
    const float* __restrict__ cb, const float* __restrict__ dw1,
    const float* __restrict__ db1, float* __restrict__ T1)
{
  int bid = blockIdx.x;
  int tid = threadIdx.x;
  if (bid < 512) {                    // init
    int i = bid * 256 + tid;
    if (i < 64) lossA[i] = 0.f;
    pk[i] = 0xFFFFFFFFFFFFFFFFull;
  } else if (bid < 520) {             // wtrans dec_w2 (2048 elems)
    int i = (bid - 512) * 256 + tid;
    if (i < 64 * 32) dev_wtrans_one(dec_w2, k2a, i);
  } else if (bid == 520) {            // wtransq dec_w3 (192 elems, k2t layout)
    int i = tid;
    if (i < 192) {
      float W[3][3];
#pragma unroll
      for (int ty = 0; ty < 3; ++ty)
#pragma unroll
        for (int tx = 0; tx < 3; ++tx) W[ty][tx] = dec_w3[i * 9 + ty * 3 + tx];
      const float A[2][3][3] = {
          {{.75f, .25f, 0.f}, {.25f, .75f, 0.f}, {0.f, .75f, .25f}},
          {{.25f, .75f, 0.f}, {0.f, .75f, .25f}, {0.f, .25f, .75f}}};
#pragma unroll
      for (int py = 0; py < 2; ++py)
#pragma unroll
        for (int px = 0; px < 2; ++px)
#pragma unroll
          for (int a = 0; a < 3; ++a)
#pragma unroll
            for (int b = 0; b < 3; ++b) {
              float v = 0.f;
#pragma unroll
              for (int ty = 0; ty < 3; ++ty)
#pragma unroll
                for (int tx = 0; tx < 3; ++tx)
                  v += W[ty][tx] * A[py][ty][a] * A[px][tx][b];
              k2t[((size_t)i * 9 + a * 3 + b) * 4 + (py * 2 + px)] = v;
            }
    }
  } else if (bid < 593) {             // wt2 (18432 elems)
    int i = (bid - 521) * 256 + tid;
    if (i < WT2_FLOATS) {
      int j = i & 15;
      int r = i >> 4;
      int ci = r & 63;
      int s = r >> 6;
      int tap = s % 9;
      int cg = s / 9;
      int co = cg * 16 + j;
      wT[i] = enc_w2[((size_t)co * C1 + ci) * 9 + tap];
    }
  } else {                            // gtab1 (16384 elems)
    int g = (bid - 593) * 256 + tid;
    int e = g >> 5, ci = g & 31;
    const float* c = cb + e * Dd;
    const float* wr = dw1 + ci * Dd;
    float a = 0.f;
#pragma unroll
    for (int d = 0; d < Dd; ++d) a += c[d] * wr[d];
    a += db1[ci];
    T1[g] = a > 0.f ? a : 0.f;
  }
}

// ---------- G[e][ab][co][ph] ----------
__global__ __launch_bounds__(256) void k_gtab2(
    const float* __restrict__ k2a, const float* __restrict__ T1,
    float* __restrict__ G)
{
  int e = blockIdx.x;
  int tid = threadIdx.x;
  int co = tid >> 2, ph = tid & 3;
  __shared__ float sT[32];
  if (tid < 32) sT[tid] = T1[e * 32 + tid];
  __syncthreads();
  float acc[9];
#pragma unroll
  for (int ab = 0; ab < 9; ++ab) acc[ab] = 0.f;
  for (int ci = 0; ci < 32; ++ci) {
    float tv = sT[ci];
    const float* kp = k2a + (size_t)(co * 32 + ci) * 36 + ph * 9;
#pragma unroll
    for (int ab = 0; ab < 9; ++ab) acc[ab] += tv * kp[ab];
  }
#pragma unroll
  for (int ab = 0; ab < 9; ++ab)
    G[((size_t)e * 9 + ab) * 256 + tid] = acc[ab];
}

// ---------- enc conv1: 3->64, 3x3, s2, p1, ReLU; NHWC output ----------
__global__ __launch_bounds__(256) void k_conv1(
    const float* __restrict__ x, const float* __restrict__ w,
    const float* __restrict__ b, float* __restrict__ h1, int n0)
{
  int bid = blockIdx.x;
  int xt = bid & 1, yt = (bid >> 1) & 15, cc = (bid >> 5) & 3, n = bid >> 7;
  int X0 = xt * 64, Y0 = yt * 8, co0 = cc * 16;
  __shared__ float sIn[3][17][130];
  int tid = threadIdx.x;
  for (int i = tid; i < 3 * 17 * 130; i += 256) {
    int ci = i / (17 * 130);
    int rr = (i / 130) % 17;
    int ccx = i % 130;
    int gy = 2 * Y0 - 1 + rr, gx = 2 * X0 - 1 + ccx;
    float v = 0.f;
    if (gy >= 0 && gy < Hin && gx >= 0 && gx < Win)
      v = x[(((size_t)(n0 + n) * 3 + ci) * Hin + gy) * Win + gx];
    sIn[ci][rr][ccx] = v;
  }
  __syncthreads();
  int lx = tid & 63, ys = tid >> 6;
  float acc[16][2];
#pragma unroll
  for (int c = 0; c < 16; ++c) { acc[c][0] = 0.f; acc[c][1] = 0.f; }
#pragma unroll
  for (int ci = 0; ci < 3; ++ci)
#pragma unroll
    for (int ky = 0; ky < 3; ++ky)
#pragma unroll
      for (int kx = 0; kx < 3; ++kx) {
        float u0 = sIn[ci][2 * ys + ky][2 * lx + kx];
        float u1 = sIn[ci][2 * ys + 8 + ky][2 * lx + kx];
#pragma unroll
        for (int c = 0; c < 16; ++c) {
          float wv = w[((co0 + c) * 3 + ci) * 9 + ky * 3 + kx];
          acc[c][0] += u0 * wv;
          acc[c][1] += u1 * wv;
        }
      }
  size_t p0 = (((size_t)n * H1 + Y0 + ys) * W1 + X0 + lx) * C1 + co0;
  size_t p1 = (((size_t)n * H1 + Y0 + ys + 4) * W1 + X0 + lx) * C1 + co0;
#pragma unroll
  for (int c = 0; c < 16; c += 4) {
    float4 s0, s1;
    float bv;
    bv = b[co0 + c + 0];
    s0.x = acc[c + 0][0] + bv; s1.x = acc[c + 0][1] + bv;
    bv = b[co0 + c + 1];
    s0.y = acc[c + 1][0] + bv; s1.y = acc[c + 1][1] + bv;
    bv = b[co0 + c + 2];
    s0.z = acc[c + 2][0] + bv; s1.z = acc[c + 2][1] + bv;
    bv = b[co0 + c + 3];
    s0.w = acc[c + 3][0] + bv; s1.w = acc[c + 3][1] + bv;
    s0.x = s0.x > 0.f ? s0.x : 0.f; s0.y = s0.y > 0.f ? s0.y : 0.f;
    s0.z = s0.z > 0.f ? s0.z : 0.f; s0.w = s0.w > 0.f ? s0.w : 0.f;
    s1.x = s1.x > 0.f ? s1.x : 0.f; s1.y = s1.y > 0.f ? s1.y : 0.f;
    s1.z = s1.z > 0.f ? s1.z : 0.f; s1.w = s1.w > 0.f ? s1.w : 0.f;
    *(float4*)&h1[p0 + c] = s0;
    *(float4*)&h1[p1 + c] = s1;
  }
}

// ---------- enc conv2: 64->32, 3x3, s2, p1, ReLU (NHWC in, barrier-free) ----------
__global__ __launch_bounds__(256) void k_conv2(
    const float* __restrict__ h1n, const float* __restrict__ wT,
    const float* __restrict__ b, float* __restrict__ h2)
{
  int bid = blockIdx.x;
  int yt = bid & 15, cg = (bid >> 4) & 1, n = bid >> 5;
  int tid = threadIdx.x;
  int x = tid & 63, y = yt * 4 + (tid >> 6);
  int co0 = cg * 16;
  float acc[16];
#pragma unroll
  for (int j = 0; j < 16; ++j) acc[j] = 0.f;
  const float* wg = wT + (size_t)cg * (9 * 64 * 16);
#pragma unroll 1
  for (int ky = 0; ky < 3; ++ky) {
    int gy = 2 * y - 1 + ky;
    if (gy < 0 || gy >= H1) continue;     // wave-uniform (y uniform per wave)
    const float* rowbase = h1n + ((size_t)n * H1 + gy) * W1 * C1;
#pragma unroll 1
    for (int kx = 0; kx < 3; ++kx) {
      int gx = 2 * x - 1 + kx;            // max 127; only gx=-1 possible OOB
      bool ok = (gx >= 0);
      const float4* ip =
          (const float4*)(rowbase + (size_t)(ok ? gx : 0) * C1);
      const float* wp = wg + (ky * 3 + kx) * (64 * 16);
#pragma unroll 4
      for (int c4 = 0; c4 < 16; ++c4) {
        float4 u = ip[c4];
        if (!ok) { u.x = 0.f; u.y = 0.f; u.z = 0.f; u.w = 0.f; }
        const float* w4 = wp + c4 * 64;
#pragma unroll
        for (int j = 0; j < 16; ++j) {
          acc[j] = __builtin_fmaf(u.x, w4[j], acc[j]);
          acc[j] = __builtin_fmaf(u.y, w4[16 + j], acc[j]);
          acc[j] = __builtin_fmaf(u.z, w4[32 + j], acc[j]);
          acc[j] = __builtin_fmaf(u.w, w4[48 + j], acc[j]);
        }
      }
    }
  }
#pragma unroll
  for (int j = 0; j < 16; ++j) {
    float v = acc[j] + b[co0 + j];
    v = v > 0.f ? v : 0.f;
    h2[(((size_t)n * C2 + co0 + j) * H2 + y) * W2 + x] = v;
  }
}

// ---------- enc conv3 (1x1, 32->64) -> z ; also writes z2[row] = sum(z^2) ----------
__global__ __launch_bounds__(256) void k_conv3z(
    const float* __restrict__ h2, const float* __restrict__ w,
    const float* __restrict__ b, float* __restrict__ z,
    float* __restrict__ z2g, int row0)
{
  int bid = blockIdx.x;
  int y = bid & 63, n = bid >> 6;
  __shared__ float sH[C2][64];
  __shared__ float sW[Dd * 33];
  int tid = threadIdx.x;
  for (int i = tid; i < C2 * 64; i += 256) {
    int ci = i >> 6, xx = i & 63;
    sH[ci][xx] = h2[((n * C2 + ci) * H2 + y) * W2 + xx];
  }
  for (int i = tid; i < Dd * C2; i += 256) {
    int d = i >> 5, ci = i & 31;
    sW[d * 33 + ci] = w[i];
  }
  __syncthreads();
  int dg = tid & 3, lx = tid >> 2;
  float acc[16];
#pragma unroll
  for (int j = 0; j < 16; ++j) acc[j] = 0.f;
  for (int ci = 0; ci < C2; ++ci) {
    float u = sH[ci][lx];
#pragma unroll
    for (int j = 0; j < 16; ++j)
      acc[j] += u * sW[(dg * 16 + j) * 33 + ci];
  }
  int row = (n * H2 + y) * W2 + lx;
  float s2 = 0.f;
#pragma unroll
  for (int j = 0; j < 16; ++j) {
    float v = acc[j] + b[dg * 16 + j];
    z[row * Dd + dg * 16 + j] = v;
    s2 = __builtin_fmaf(v, v, s2);
  }
  s2 += __shfl_xor(s2, 1);
  s2 += __shfl_xor(s2, 2);
  if (dg == 0) z2g[row0 + row] = s2;
}

// ---------- VQ main ----------
// v7: 2D grid (blockIdx.y = codebook split). With sp = bid&3, co-resident
// blocks used 4 DIFFERENT 32KB splits -> 128KB scalar working set vs 16KB
// K$ -> uniform s_load chains missed to L2 (~200cy), half-hidden at ~3
// waves/SIMD. x-fastest dispatch makes neighbors share the same split.
// atomicMin is order-independent; body is the proven round-10/13 version.
__global__ __launch_bounds__(256, 1) void k_vq(
    const float* __restrict__ z, const float* __restrict__ cbf,
    unsigned long long* __restrict__ pk, int row0)
{
  __shared__ float c2s[128];
  int sp = blockIdx.y, rb = blockIdx.x;
  int c0 = sp * 128;
  int tid = threadIdx.x;
  if (tid < 128) {
    const float* cr = cbf + (size_t)(c0 + tid) * Dd;
    float s = 0.f;
#pragma unroll
    for (int d = 0; d < Dd; ++d) { float v = cr[d]; s += v * v; }
    c2s[tid] = s;
  }
  __syncthreads();
  int r = rb * 256 + tid;
  const float4* zp = (const float4*)(z + (size_t)r * Dd);
  float4 zr[16];
#pragma unroll
  for (int i = 0; i < 16; ++i) zr[i] = zp[i];
  // pin all 64 components in VGPRs
#pragma unroll
  for (int i = 0; i < 16; i += 4) {
    asm volatile("" : "+v"(zr[i].x), "+v"(zr[i].y), "+v"(zr[i].z), "+v"(zr[i].w),
                      "+v"(zr[i+1].x), "+v"(zr[i+1].y), "+v"(zr[i+1].z), "+v"(zr[i+1].w),
                      "+v"(zr[i+2].x), "+v"(zr[i+2].y), "+v"(zr[i+2].z), "+v"(zr[i+2].w),
                      "+v"(zr[i+3].x), "+v"(zr[i+3].y), "+v"(zr[i+3].z), "+v"(zr[i+3].w));
  }
  float best = 1e30f; int bidx = c0;
#pragma unroll 2
  for (int c = 0; c < 128; ++c) {
    const float4* __restrict__ cr4 = (const float4*)(cbf + (size_t)(c0 + c) * Dd);
    float d0 = 0.f, d1 = 0.f, d2a = 0.f, d3 = 0.f;
#pragma unroll
    for (int i = 0; i < 16; ++i) {
      float4 cv = cr4[i];
      d0 = __builtin_fmaf(zr[i].x, cv.x, d0);
      d1 = __builtin_fmaf(zr[i].y, cv.y, d1);
      d2a = __builtin_fmaf(zr[i].z, cv.z, d2a);
      d3 = __builtin_fmaf(zr[i].w, cv.w, d3);
    }
    float dot = (d0 + d1) + (d2a + d3);
    float dist = c2s[c] - 2.f * dot;
    if (dist < best) { best = dist; bidx = c0 + c; }
  }
  unsigned int u = __float_as_uint(best);
  unsigned int key32 = (u & 0x80000000u) ? ~u : (u | 0x80000000u);
  unsigned long long key =
      ((unsigned long long)key32 << 32) | (unsigned int)bidx;
  atomicMin(&pk[row0 + r], key);
}

// ---------- VQ merge: decode pk key; ||z-c||^2 = dist + ||z||^2 ----------
__global__ __launch_bounds__(256) void k_vqfin(
    const unsigned long long* __restrict__ pk, const float* __restrict__ z2g,
    int* __restrict__ idx, float* __restrict__ lossA, int row0)
{
  int r = blockIdx.x * 256 + threadIdx.x;
  int gi = row0 + r;
  unsigned long long key = pk[gi];
  int bidx = (int)(key & 0xFFFFFFFFull);
  idx[gi] = bidx;
  unsigned int k32 = (unsigned int)(key >> 32);
  unsigned int u = (k32 & 0x80000000u) ? (k32 & 0x7FFFFFFFu) : ~k32;
  float ls = __uint_as_float(u) + z2g[gi];
#pragma unroll
  for (int off = 32; off > 0; off >>= 1) ls += __shfl_down(ls, off);
  if ((threadIdx.x & 63) == 0) atomicAdd(lossA, ls);
}

__global__ void k_loss_final(const float* __restrict__ a, float* __restrict__ out)
{
  if (threadIdx.x == 0) {
    float l = a[0] / (float)(ROWS * Dd);
    out[0] = l;
    out[1] = l;
  }
}

// ---------- d2 interior via G-table gather ----------
// NOTE: writes the FULL tile incl. ring (approximate); k_border_a then
// overwrites the ring with exact values. MUST remain a separate, later
// dispatch (round-15 fusion raced and failed correctness).
__global__ __launch_bounds__(256) void k_upg(
    const int* __restrict__ idx, const float* __restrict__ G,
    const float* __restrict__ bias, float* __restrict__ O, int row0)
{
  int bid = blockIdx.x;
  int tx = bid & 3; bid >>= 2;
  int ty = bid & 3; bid >>= 2;
  int cog = bid & 7; bid >>= 3;
  int n = bid;
  int Y0 = ty * 16, X0 = tx * 16, co0 = cog * 8;
  __shared__ int sIdx[18 * 18];
  int tid = threadIdx.x;
  int base = row0 + (n << 12);
  for (int i = tid; i < 324; i += 256) {
    int r = i / 18, c = i % 18;
    int gy = Y0 - 1 + r; gy = gy < 0 ? 0 : (gy > 63 ? 63 : gy);
    int gx = X0 - 1 + c; gx = gx < 0 ? 0 : (gx > 63 ? 63 : gx);
    sIdx[i] = idx[base + gy * 64 + gx];
  }
  __syncthreads();
  int xx = tid & 15, yy = tid >> 4;
  float4 acc[8];
#pragma unroll
  for (int j = 0; j < 8; ++j) acc[j] = make_float4(0.f, 0.f, 0.f, 0.f);
#pragma unroll
  for (int a = 0; a < 3; ++a)
#pragma unroll
    for (int b = 0; b < 3; ++b) {
      int e = sIdx[(yy + a) * 18 + xx + b];
      const float4* gp =
          (const float4*)(G + ((size_t)(e * 9 + a * 3 + b) * 256) + co0 * 4);
#pragma unroll
      for (int j = 0; j < 8; ++j) {
        float4 gv = gp[j];
        acc[j].x += gv.x; acc[j].y += gv.y;
        acc[j].z += gv.z; acc[j].w += gv.w;
      }
    }
  int oy = 2 * (Y0 + yy), ox = 2 * (X0 + xx);
#pragma unroll
  for (int j = 0; j < 8; ++j) {
    int co = co0 + j;
    float bv = bias[co];
    float2 r0, r1;
    r0.x = acc[j].x + bv; r0.y = acc[j].y + bv;
    r1.x = acc[j].z + bv; r1.y = acc[j].w + bv;
    r0.x = r0.x > 0.f ? r0.x : 0.f; r0.y = r0.y > 0.f ? r0.y : 0.f;
    r1.x = r1.x > 0.f ? r1.x : 0.f; r1.y = r1.y > 0.f ? r1.y : 0.f;
    size_t o = ((size_t)(n * 64 + co) * 128 + oy) * 128 + ox;
    *(float2*)&O[o] = r0;
    *(float2*)&O[o + 128] = r1;
  }
}

// ---------- exact d2 border ring via T1-gathered LDS strips ----------
__global__ __launch_bounds__(256) void k_border_a(
    const int* __restrict__ idx, const float* __restrict__ T1,
    const float* __restrict__ w2, const float* __restrict__ b2,
    float* __restrict__ d2, int row0)
{
  int bid = blockIdx.x;
  int ch = bid & 1; bid >>= 1;
  int side = bid & 3; bid >>= 2;
  int n = bid;
  bool hside = side < 2;
  int rbase = (side == 1) ? 62 : 0;   // d1 rows for h-sides
  int cbase = (side == 3) ? 62 : 0;   // d1 cols for v-sides
  __shared__ int sE[128];
  __shared__ float sD[32 * 128];      // [ci][strip]
  int tid = threadIdx.x;
  if (tid < 128) {
    int yy, xx;
    if (hside) { yy = rbase + (tid >> 6); xx = tid & 63; }
    else       { yy = tid >> 1; xx = cbase + (tid & 1); }
    sE[tid] = idx[row0 + (n << 12) + yy * 64 + xx];
  }
  __syncthreads();
  for (int t = tid; t < 32 * 128; t += 256) {
    int ci = t >> 7, j = t & 127;
    sD[t] = T1[sE[j] * 32 + ci];
  }
  __syncthreads();
  int px = tid & 127, q = tid >> 7;
  int co0 = (ch * 2 + q) * 16;
  int u, v;
  if (side == 0)      { u = 0;   v = px; }
  else if (side == 1) { u = 127; v = px; }
  else if (side == 2) { u = px;  v = 0;   if (px == 0 || px == 127) return; }
  else                { u = px;  v = 127; if (px == 0 || px == 127) return; }
  float acc[16];
#pragma unroll
  for (int j = 0; j < 16; ++j) acc[j] = 0.f;
  for (int ci = 0; ci < 32; ++ci) {
    const float* P = sD + ci * 128;
    float u9[9];
#pragma unroll
    for (int dy = -1; dy <= 1; ++dy)
#pragma unroll
      for (int dx = -1; dx <= 1; ++dx) {
        int uy = u + dy, ux = v + dx;
        float val = 0.f;
        if (uy >= 0 && uy < 128 && ux >= 0 && ux < 128) {
          int ky0, ky1, kx0, kx1; float ay0, ax0;
          if (uy & 1) { ky0 = uy >> 1; ky1 = ky0 + 1; ay0 = .75f; }
          else        { ky1 = uy >> 1; ky0 = ky1 - 1; ay0 = .25f; }
          if (ux & 1) { kx0 = ux >> 1; kx1 = kx0 + 1; ax0 = .75f; }
          else        { kx1 = ux >> 1; kx0 = kx1 - 1; ax0 = .25f; }
          ky0 = ky0 < 0 ? 0 : (ky0 > 63 ? 63 : ky0);
          ky1 = ky1 < 0 ? 0 : (ky1 > 63 ? 63 : ky1);
          kx0 = kx0 < 0 ? 0 : (kx0 > 63 ? 63 : kx0);
          kx1 = kx1 < 0 ? 0 : (kx1 > 63 ? 63 : kx1);
          int i00, i01, i10, i11;
          if (hside) {
            i00 = (ky0 - rbase) * 64 + kx0; i01 = (ky0 - rbase) * 64 + kx1;
            i10 = (ky1 - rbase) * 64 + kx0; i11 = (ky1 - rbase) * 64 + kx1;
          } else {
            i00 = ky0 * 2 + (kx0 - cbase); i01 = ky0 * 2 + (kx1 - cbase);
            i10 = ky1 * 2 + (kx0 - cbase); i11 = ky1 * 2 + (kx1 - cbase);
          }
          float ay1 = 1.f - ay0, ax1 = 1.f - ax0;
          val = ay0 * (ax0 * P[i00] + ax1 * P[i01]) +
                ay1 * (ax0 * P[i10] + ax1 * P[i11]);
        }
        u9[(dy + 1) * 3 + (dx + 1)] = val;
      }
#pragma unroll
    for (int j = 0; j < 16; ++j) {
      const float* wp = w2 + ((size_t)((co0 + j) * 32 + ci)) * 9;
#pragma unroll
      for (int tp = 0; tp < 9; ++tp) acc[j] += u9[tp] * wp[tp];
    }
  }
#pragma unroll
  for (int j = 0; j < 16; ++j) {
    int co = co0 + j;
    float val = acc[j] + b2[co];
    val = val > 0.f ? val : 0.f;
    d2[((size_t)(n * 64 + co) * 128 + u) * 128 + v] = val;
  }
}

// ---------- recon interior: composed conv (LDS weights + T14) ----------
__global__ __launch_bounds__(128) void k_upconv2x_b(
    const float* __restrict__ I, const float* __restrict__ k2t,
    const float* __restrict__ bias, float* __restrict__ O, int n0)
{
  constexpr int Hi = 128, Ci = 64, Co = 3;
  constexpr int NSTG = 4 * 10 * 34;     // 1360 staged input elems/phase
  constexpr int NW = 432;               // staged weight floats/phase
  int bid = blockIdx.x;
  int tx = bid & 3; bid >>= 2;       // 4 x-tiles of 32
  int ty = bid & 15; bid >>= 4;      // 16 y-tiles of 8
  int n = bid;
  int Y0 = ty * 8, X0 = tx * 32;
  __shared__ float sI[4][10 * 35];
  __shared__ __align__(16) float sW[NW];
  int tid = threadIdx.x;
  int lx = tid & 15, ly = tid >> 4;  // 16x8 threads, 2x1 low-res px each

  int soff[11], ldst[11];
#pragma unroll
  for (int k = 0; k < 11; ++k) {
    int i = tid + k * 128;
    if (i < NSTG) {
      int s = i / 340, r2 = i % 340;
      int rr = r2 / 34, cc2 = r2 % 34;
      int gy = Y0 - 1 + rr; gy = gy < 0 ? 0 : (gy > Hi - 1 ? Hi - 1 : gy);
      int gx = X0 - 1 + cc2; gx = gx < 0 ? 0 : (gx > Hi - 1 ? Hi - 1 : gx);
      soff[k] = s * (Hi * Hi) + gy * Hi + gx;
      ldst[k] = s * 350 + rr * 35 + cc2;
    } else {
      soff[k] = -1;
      ldst[k] = 0;
    }
  }
  int wsrc[4];
#pragma unroll
  for (int k = 0; k < 4; ++k) {
    int i = tid + k * 128;
    if (i < NW) {
      int j = i / 144;
      wsrc[k] = i + j * 2160;
    } else {
      wsrc[k] = -1;
    }
  }
  const float* Ibase = I + (size_t)n * Ci * (Hi * Hi);

  float rbuf[11];
#pragma unroll
  for (int k = 0; k < 11; ++k)
    if (soff[k] >= 0) rbuf[k] = Ibase[soff[k]];
  float rw[4];
#pragma unroll
  for (int k = 0; k < 4; ++k)
    if (wsrc[k] >= 0) rw[k] = k2t[wsrc[k]];

  float4 acc[3][2];
#pragma unroll
  for (int j = 0; j < 3; ++j)
#pragma unroll
    for (int py = 0; py < 2; ++py) acc[j][py] = make_float4(0.f, 0.f, 0.f, 0.f);

  for (int c0 = 0; c0 < Ci; c0 += 4) {
    __syncthreads();
#pragma unroll
    for (int k = 0; k < 11; ++k)
      if (soff[k] >= 0) ((float*)sI)[ldst[k]] = rbuf[k];
#pragma unroll
    for (int k = 0; k < 4; ++k)
      if (wsrc[k] >= 0) sW[tid + k * 128] = rw[k];
    __syncthreads();
    if (c0 + 4 < Ci) {
      const float* Inext = Ibase + (size_t)(c0 + 4) * (Hi * Hi);
#pragma unroll
      for (int k = 0; k < 11; ++k)
        if (soff[k] >= 0) rbuf[k] = Inext[soff[k]];
      const float* Wnext = k2t + (size_t)(c0 + 4) * 36;
#pragma unroll
      for (int k = 0; k < 4; ++k)
        if (wsrc[k] >= 0) rw[k] = Wnext[wsrc[k]];
    }
#pragma unroll
    for (int s = 0; s < 4; ++s) {
      float t[3][4];
#pragma unroll
      for (int r = 0; r < 3; ++r)
#pragma unroll
        for (int c = 0; c < 4; ++c)
          t[r][c] = sI[s][(ly + r) * 35 + 2 * lx + c];
#pragma unroll
      for (int j = 0; j < 3; ++j) {
        const float* wj = &sW[(j * 4 + s) * 36];
#pragma unroll
        for (int a = 0; a < 3; ++a)
#pragma unroll
          for (int b = 0; b < 3; ++b) {
            float4 wv = *(const float4*)&wj[(a * 3 + b) * 4];
            float w00 = wv.x;
            float w01 = wv.y;
            float w10 = wv.z;
            float w11 = wv.w;
            float i0 = t[a][b];
            float i1 = t[a][b + 1];
            acc[j][0].x += i0 * w00;
            acc[j][0].y += i0 * w01;
            acc[j][0].z += i1 * w00;
            acc[j][0].w += i1 * w01;
            acc[j][1].x += i0 * w10;
            acc[j][1].y += i0 * w11;
            acc[j][1].z += i1 * w10;
            acc[j][1].w += i1 * w11;
          }
      }
    }
  }
  int ox = 2 * X0 + 4 * lx;
  int oy0 = 2 * (Y0 + ly);
#pragma unroll
  for (int j = 0; j < 3; ++j) {
    float bv = bias[j];
#pragma unroll
    for (int py = 0; py < 2; ++py) {
      float4 v = acc[j][py];
      v.x += bv; v.y += bv; v.z += bv; v.w += bv;
      size_t off = (((size_t)((n0 + n) * Co + j)) * 256 + oy0 + py) * 256 + ox;
      *(float4*)&O[off] = v;
    }
  }
}

// ---------- exact recon border ring via d2-strip LDS ----------
__global__ __launch_bounds__(256) void k_border_b(
    const float* __restrict__ d2, const float* __restrict__ w3,
    const float* __restrict__ b3, float* __restrict__ O, int n0)
{
  int bid = blockIdx.x;
  int side = bid & 3; int n = bid >> 2;
  bool hside = side < 2;
  int rbase = (side == 1) ? 126 : 0;
  int cbase = (side == 3) ? 126 : 0;
  __shared__ float sD[32 * 256];  // [ci][strip]
  int tid = threadIdx.x;
  int px = tid;
  int u, v;
  if (side == 0)      { u = 0;   v = px; }
  else if (side == 1) { u = 255; v = px; }
  else if (side == 2) { u = px;  v = 0; }
  else                { u = px;  v = 255; }
  bool active = hside || (px != 0 && px != 255);
  float a0 = 0.f, a1 = 0.f, a2 = 0.f;
  for (int half = 0; half < 2; ++half) {
    __syncthreads();
    int cib = half * 32;
    for (int t = tid; t < 32 * 256; t += 256) {
      int ci = t >> 8, j = t & 255;
      int yy, xx;
      if (hside) { yy = rbase + (j >> 7); xx = j & 127; }
      else       { yy = j >> 1; xx = cbase + (j & 1); }
      sD[t] = d2[(((size_t)n * 64 + cib + ci) * 128 + yy) * 128 + xx];
    }
    __syncthreads();
    if (active) {
      for (int ci = 0; ci < 32; ++ci) {
        const float* P = sD + ci * 256;
        float u9[9];
#pragma unroll
        for (int dy = -1; dy <= 1; ++dy)
#pragma unroll
          for (int dx = -1; dx <= 1; ++dx) {
            int uy = u + dy, ux = v + dx;
            float val = 0.f;
            if (uy >= 0 && uy < 256 && ux >= 0 && ux < 256) {
              int ky0, ky1, kx0, kx1; float ay0, ax0;
              if (uy & 1) { ky0 = uy >> 1; ky1 = ky0 + 1; ay0 = .75f; }
              else        { ky1 = uy >> 1; ky0 = ky1 - 1; ay0 = .25f; }
              if (ux & 1) { kx0 = ux >> 1; kx1 = kx0 + 1; ax0 = .75f; }
              else        { kx1 = ux >> 1; kx0 = kx1 - 1; ax0 = .25f; }
              ky0 = ky0 < 0 ? 0 : (ky0 > 127 ? 127 : ky0);
              ky1 = ky1 < 0 ? 0 : (ky1 > 127 ? 127 : ky1);
              kx0 = kx0 < 0 ? 0 : (kx0 > 127 ? 127 : kx0);
              kx1 = kx1 < 0 ? 0 : (kx1 > 127 ? 127 : kx1);
              int i00, i01, i10, i11;
              if (hside) {
                i00 = (ky0 - rbase) * 128 + kx0; i01 = (ky0 - rbase) * 128 + kx1;
                i10 = (ky1 - rbase) * 128 + kx0; i11 = (ky1 - rbase) * 128 + kx1;
              } else {
                i00 = ky0 * 2 + (kx0 - cbase); i01 = ky0 * 2 + (kx1 - cbase);
                i10 = ky1 * 2 + (kx0 - cbase); i11 = ky1 * 2 + (kx1 - cbase);
              }
              float ay1 = 1.f - ay0, ax1 = 1.f - ax0;
              val = ay0 * (ax0 * P[i00] + ax1 * P[i01]) +
                    ay1 * (ax0 * P[i10] + ax1 * P[i11]);
            }
            u9[(dy + 1) * 3 + (dx + 1)] = val;
          }
        const float* w0 = w3 + ((size_t)(0 * 64 + cib + ci)) * 9;
        const float* w1 = w3 + ((size_t)(1 * 64 + cib + ci)) * 9;
        const float* w2p = w3 + ((size_t)(2 * 64 + cib + ci)) * 9;
#pragma unroll
        for (int tp = 0; tp < 9; ++tp) {
          a0 += u9[tp] * w0[tp];
          a1 += u9[tp] * w1[tp];
          a2 += u9[tp] * w2p[tp];
        }
      }
    }
  }
  if (active) {
    size_t b = ((size_t)(n0 + n) * 3) * 65536 + (size_t)u * 256 + v;
    O[b] = a0 + b3[0];
    O[b + 65536] = a1 + b3[1];
    O[b + 131072] = a2 + b3[2];
  }
}

extern "C" void kernel_launch(void* const* d_in, const int* in_sizes, int n_in,
                              void* d_out, int out_size, void* d_ws, size_t ws_size,
                              hipStream_t stream)
{
  const float* x      = (const float*)d_in[0];
  const float* cb     = (const float*)d_in[1];
  const float* enc_w1 = (const float*)d_in[2];
  const float* enc_b1 = (const float*)d_in[3];
  const float* enc_w2 = (const float*)d_in[4];
  const float* enc_b2 = (const float*)d_in[5];
  const float* enc_w3 = (const float*)d_in[6];
  const float* enc_b3 = (const float*)d_in[7];
  const float* dec_w1 = (const float*)d_in[8];
  const float* dec_b1 = (const float*)d_in[9];
  const float* dec_w2 = (const float*)d_in[10];
  const float* dec_b2 = (const float*)d_in[11];
  const float* dec_w3 = (const float*)d_in[12];
  const float* dec_b3 = (const float*)d_in[13];

  float* ws = (float*)d_ws;
  float* lossA = ws;
  int* idx = (int*)(lossA + 64);
  unsigned long long* pk = (unsigned long long*)(idx + ROWS);
  float* z2g = (float*)(pk + ROWS);
  float* k2a = z2g + ROWS;
  float* k2b = k2a + K2A_FLOATS;   // k2t layout for upconv
  float* T1  = k2b + K2B_FLOATS;
  float* G   = T1 + T1_FLOATS;
  float* wT2 = G + G_FLOATS + 64;
  float* chunkbuf = wT2 + WT2_FLOATS;

  int CH = 1;
  for (int c = 32; c >= 1; c >>= 1) {
    size_t need = ((size_t)FIX_FLOATS + (size_t)(H1_PER_N + Z_PER_N + H2_PER_N) * c) * 4;
    if (need <= ws_size) { CH = c; break; }
  }
  float* h1 = chunkbuf;                   // NHWC for encoder; d2 buffer for decoder
  float* z  = h1 + (size_t)H1_PER_N * CH;
  float* h2 = z + (size_t)Z_PER_N * CH;

  // fused setup: init | wtrans | wtransq | wt2 | gtab1 (657 blocks)
  k_setup<<<657, 256, 0, stream>>>(lossA, pk, dec_w2, k2a, dec_w3, k2b,
                                   enc_w2, wT2, cb, dec_w1, dec_b1, T1);
  k_gtab2<<<Kc, 256, 0, stream>>>(k2a, T1, G);

  float* out = (float*)d_out;

  for (int n0 = 0; n0 < Bn; n0 += CH) {
    int row0 = n0 * H2 * W2;
    k_conv1<<<CH * 128, 256, 0, stream>>>(x, enc_w1, enc_b1, h1, n0);
    k_conv2<<<CH * 32, 256, 0, stream>>>(h1, wT2, enc_b2, h2);
    k_conv3z<<<CH * 64, 256, 0, stream>>>(h2, enc_w3, enc_b3, z, z2g, row0);
    k_vq<<<dim3(CH * 16, 4), 256, 0, stream>>>(z, cb, pk, row0);
    k_vqfin<<<CH * 16, 256, 0, stream>>>(pk, z2g, idx, lossA, row0);
    // d2 interior (composed) then exact ring -- ORDER REQUIRED (ring overwrite)
    k_upg<<<CH * 8 * 16, 256, 0, stream>>>(idx, G, dec_b2, h1, row0);
    k_border_a<<<CH * 4 * 2, 256, 0, stream>>>(idx, T1, dec_w2, dec_b2, h1, row0);
    // recon interior (composed) then exact ring
    k_upconv2x_b<<<CH * 64, 128, 0, stream>>>(h1, k2b, dec_b3, out + 2, n0);
    k_border_b<<<CH * 4, 256, 0, stream>>>(h1, dec_w3, dec_b3, out + 2, n0);
  }
  k_loss_final<<<1, 64, 0, stream>>>(lossA, out);
}

// Round 17
// 859.437 us; speedup vs baseline: 1.0264x; 1.0264x over previous
//
#include <hip/hip_runtime.h>
#include <hip/hip_bf16.h>

static constexpr int Bn = 32;
static constexpr int Hin = 256, Win = 256;
static constexpr int C1 = 64, H1 = 128, W1 = 128;
static constexpr int C2 = 32, H2 = 64, W2 = 64;
static constexpr int Dd = 64;    // latent dim
static constexpr int Kc = 512;   // codebook entries
static constexpr int ROWS = Bn * H2 * W2;  // 131072

// ws layout (floats): lossA(64) | idx | pk | z2 | k2a | k2b | T1 | G | wT2 | chunk
static constexpr int K2A_FLOATS = 64 * 32 * 36;   // 73728
static constexpr int K2B_FLOATS = 3 * 64 * 36;    // 6912 (k2t layout)
static constexpr int T1_FLOATS  = Kc * C2;        // 16384
static constexpr int G_FLOATS   = Kc * 9 * 64 * 4; // 1,179,648
static constexpr int WT2_FLOATS = 2 * 9 * 64 * 16; // 18432
static constexpr int FIX_FLOATS = 64 + ROWS + 2 * ROWS + ROWS + K2A_FLOATS +
                                  K2B_FLOATS + T1_FLOATS + G_FLOATS + 64 +
                                  WT2_FLOATS;
static constexpr int H1_PER_N = C1 * H1 * W1;    // 1,048,576
static constexpr int Z_PER_N  = H2 * W2 * Dd;    // 262,144
static constexpr int H2_PER_N = C2 * H2 * W2;    // 131,072

// ---------- fused setup: init | wtrans(dec_w2) | wtransq(dec_w3) | wt2 | gtab1 ----------
__device__ __forceinline__ void dev_wtrans_one(
    const float* __restrict__ w, float* __restrict__ k2, int i)
{
  float W[3][3];
#pragma unroll
  for (int ty = 0; ty < 3; ++ty)
#pragma unroll
    for (int tx = 0; tx < 3; ++tx) W[ty][tx] = w[i * 9 + ty * 3 + tx];
  const float A[2][3][3] = {
      {{.75f, .25f, 0.f}, {.25f, .75f, 0.f}, {0.f, .75f, .25f}},
      {{.25f, .75f, 0.f}, {0.f, .75f, .25f}, {0.f, .25f, .75f}}};
#pragma unroll
  for (int py = 0; py < 2; ++py)
#pragma unroll
    for (int px = 0; px < 2; ++px)
#pragma unroll
      for (int a = 0; a < 3; ++a)
#pragma unroll
        for (int b = 0; b < 3; ++b) {
          float v = 0.f;
#pragma unroll
          for (int ty = 0; ty < 3; ++ty)
#pragma unroll
            for (int tx = 0; tx < 3; ++tx)
              v += W[ty][tx] * A[py][ty][a] * A[px][tx][b];
          k2[(size_t)i * 36 + (py * 2 + px) * 9 + a * 3 + b] = v;
        }
}

__global__ __launch_bounds__(256) void k_setup(
    float* __restrict__ lossA, unsigned long long* __restrict__ pk,
    const float* __restrict__ dec_w2, float* __restrict__ k2a,
    const float* __restrict__ dec_w3, float* __restrict__ k2t,
    const float* __restrict__ enc_w2, float* __restrict__ wT,
    const float* __restrict__ cb, const float* __restrict__ dw1,
    const float* __restrict__ db1, float* __restrict__ T1)
{
  int bid = blockIdx.x;
  int tid = threadIdx.x;
  if (bid < 512) {                    // init
    int i = bid * 256 + tid;
    if (i < 64) lossA[i] = 0.f;
    pk[i] = 0xFFFFFFFFFFFFFFFFull;
  } else if (bid < 520) {             // wtrans dec_w2 (2048 elems)
    int i = (bid - 512) * 256 + tid;
    if (i < 64 * 32) dev_wtrans_one(dec_w2, k2a, i);
  } else if (bid == 520) {            // wtransq dec_w3 (192 elems, k2t layout)
    int i = tid;
    if (i < 192) {
      float W[3][3];
#pragma unroll
      for (int ty = 0; ty < 3; ++ty)
#pragma unroll
        for (int tx = 0; tx < 3; ++tx) W[ty][tx] = dec_w3[i * 9 + ty * 3 + tx];
      const float A[2][3][3] = {
          {{.75f, .25f, 0.f}, {.25f, .75f, 0.f}, {0.f, .75f, .25f}},
          {{.25f, .75f, 0.f}, {0.f, .75f, .25f}, {0.f, .25f, .75f}}};
#pragma unroll
      for (int py = 0; py < 2; ++py)
#pragma unroll
        for (int px = 0; px < 2; ++px)
#pragma unroll
          for (int a = 0; a < 3; ++a)
#pragma unroll
            for (int b = 0; b < 3; ++b) {
              float v = 0.f;
#pragma unroll
              for (int ty = 0; ty < 3; ++ty)
#pragma unroll
                for (int tx = 0; tx < 3; ++tx)
                  v += W[ty][tx] * A[py][ty][a] * A[px][tx][b];
              k2t[((size_t)i * 9 + a * 3 + b) * 4 + (py * 2 + px)] = v;
            }
    }
  } else if (bid < 593) {             // wt2 (18432 elems)
    int i = (bid - 521) * 256 + tid;
    if (i < WT2_FLOATS) {
      int j = i & 15;
      int r = i >> 4;
      int ci = r & 63;
      int s = r >> 6;
      int tap = s % 9;
      int cg = s / 9;
      int co = cg * 16 + j;
      wT[i] = enc_w2[((size_t)co * C1 + ci) * 9 + tap];
    }
  } else {                            // gtab1 (16384 elems)
    int g = (bid - 593) * 256 + tid;
    int e = g >> 5, ci = g & 31;
    const float* c = cb + e * Dd;
    const float* wr = dw1 + ci * Dd;
    float a = 0.f;
#pragma unroll
    for (int d = 0; d < Dd; ++d) a += c[d] * wr[d];
    a += db1[ci];
    T1[g] = a > 0.f ? a : 0.f;
  }
}

// ---------- G[e][ab][co][ph] ----------
__global__ __launch_bounds__(256) void k_gtab2(
    const float* __restrict__ k2a, const float* __restrict__ T1,
    float* __restrict__ G)
{
  int e = blockIdx.x;
  int tid = threadIdx.x;
  int co = tid >> 2, ph = tid & 3;
  __shared__ float sT[32];
  if (tid < 32) sT[tid] = T1[e * 32 + tid];
  __syncthreads();
  float acc[9];
#pragma unroll
  for (int ab = 0; ab < 9; ++ab) acc[ab] = 0.f;
  for (int ci = 0; ci < 32; ++ci) {
    float tv = sT[ci];
    const float* kp = k2a + (size_t)(co * 32 + ci) * 36 + ph * 9;
#pragma unroll
    for (int ab = 0; ab < 9; ++ab) acc[ab] += tv * kp[ab];
  }
#pragma unroll
  for (int ab = 0; ab < 9; ++ab)
    G[((size_t)e * 9 + ab) * 256 + tid] = acc[ab];
}

// ---------- enc conv1: 3->64, 3x3, s2, p1, ReLU; NHWC output ----------
__global__ __launch_bounds__(256) void k_conv1(
    const float* __restrict__ x, const float* __restrict__ w,
    const float* __restrict__ b, float* __restrict__ h1, int n0)
{
  int bid = blockIdx.x;
  int xt = bid & 1, yt = (bid >> 1) & 15, cc = (bid >> 5) & 3, n = bid >> 7;
  int X0 = xt * 64, Y0 = yt * 8, co0 = cc * 16;
  __shared__ float sIn[3][17][130];
  int tid = threadIdx.x;
  for (int i = tid; i < 3 * 17 * 130; i += 256) {
    int ci = i / (17 * 130);
    int rr = (i / 130) % 17;
    int ccx = i % 130;
    int gy = 2 * Y0 - 1 + rr, gx = 2 * X0 - 1 + ccx;
    float v = 0.f;
    if (gy >= 0 && gy < Hin && gx >= 0 && gx < Win)
      v = x[(((size_t)(n0 + n) * 3 + ci) * Hin + gy) * Win + gx];
    sIn[ci][rr][ccx] = v;
  }
  __syncthreads();
  int lx = tid & 63, ys = tid >> 6;
  float acc[16][2];
#pragma unroll
  for (int c = 0; c < 16; ++c) { acc[c][0] = 0.f; acc[c][1] = 0.f; }
#pragma unroll
  for (int ci = 0; ci < 3; ++ci)
#pragma unroll
    for (int ky = 0; ky < 3; ++ky)
#pragma unroll
      for (int kx = 0; kx < 3; ++kx) {
        float u0 = sIn[ci][2 * ys + ky][2 * lx + kx];
        float u1 = sIn[ci][2 * ys + 8 + ky][2 * lx + kx];
#pragma unroll
        for (int c = 0; c < 16; ++c) {
          float wv = w[((co0 + c) * 3 + ci) * 9 + ky * 3 + kx];
          acc[c][0] += u0 * wv;
          acc[c][1] += u1 * wv;
        }
      }
  size_t p0 = (((size_t)n * H1 + Y0 + ys) * W1 + X0 + lx) * C1 + co0;
  size_t p1 = (((size_t)n * H1 + Y0 + ys + 4) * W1 + X0 + lx) * C1 + co0;
#pragma unroll
  for (int c = 0; c < 16; c += 4) {
    float4 s0, s1;
    float bv;
    bv = b[co0 + c + 0];
    s0.x = acc[c + 0][0] + bv; s1.x = acc[c + 0][1] + bv;
    bv = b[co0 + c + 1];
    s0.y = acc[c + 1][0] + bv; s1.y = acc[c + 1][1] + bv;
    bv = b[co0 + c + 2];
    s0.z = acc[c + 2][0] + bv; s1.z = acc[c + 2][1] + bv;
    bv = b[co0 + c + 3];
    s0.w = acc[c + 3][0] + bv; s1.w = acc[c + 3][1] + bv;
    s0.x = s0.x > 0.f ? s0.x : 0.f; s0.y = s0.y > 0.f ? s0.y : 0.f;
    s0.z = s0.z > 0.f ? s0.z : 0.f; s0.w = s0.w > 0.f ? s0.w : 0.f;
    s1.x = s1.x > 0.f ? s1.x : 0.f; s1.y = s1.y > 0.f ? s1.y : 0.f;
    s1.z = s1.z > 0.f ? s1.z : 0.f; s1.w = s1.w > 0.f ? s1.w : 0.f;
    *(float4*)&h1[p0 + c] = s0;
    *(float4*)&h1[p1 + c] = s1;
  }
}

// ---------- enc conv2: 64->32, 3x3, s2, p1, ReLU (NHWC in, barrier-free) ----------
__global__ __launch_bounds__(256) void k_conv2(
    const float* __restrict__ h1n, const float* __restrict__ wT,
    const float* __restrict__ b, float* __restrict__ h2)
{
  int bid = blockIdx.x;
  int yt = bid & 15, cg = (bid >> 4) & 1, n = bid >> 5;
  int tid = threadIdx.x;
  int x = tid & 63, y = yt * 4 + (tid >> 6);
  int co0 = cg * 16;
  float acc[16];
#pragma unroll
  for (int j = 0; j < 16; ++j) acc[j] = 0.f;
  const float* wg = wT + (size_t)cg * (9 * 64 * 16);
#pragma unroll 1
  for (int ky = 0; ky < 3; ++ky) {
    int gy = 2 * y - 1 + ky;
    if (gy < 0 || gy >= H1) continue;     // wave-uniform (y uniform per wave)
    const float* rowbase = h1n + ((size_t)n * H1 + gy) * W1 * C1;
#pragma unroll 1
    for (int kx = 0; kx < 3; ++kx) {
      int gx = 2 * x - 1 + kx;            // max 127; only gx=-1 possible OOB
      bool ok = (gx >= 0);
      const float4* ip =
          (const float4*)(rowbase + (size_t)(ok ? gx : 0) * C1);
      const float* wp = wg + (ky * 3 + kx) * (64 * 16);
#pragma unroll 4
      for (int c4 = 0; c4 < 16; ++c4) {
        float4 u = ip[c4];
        if (!ok) { u.x = 0.f; u.y = 0.f; u.z = 0.f; u.w = 0.f; }
        const float* w4 = wp + c4 * 64;
#pragma unroll
        for (int j = 0; j < 16; ++j) {
          acc[j] = __builtin_fmaf(u.x, w4[j], acc[j]);
          acc[j] = __builtin_fmaf(u.y, w4[16 + j], acc[j]);
          acc[j] = __builtin_fmaf(u.z, w4[32 + j], acc[j]);
          acc[j] = __builtin_fmaf(u.w, w4[48 + j], acc[j]);
        }
      }
    }
  }
#pragma unroll
  for (int j = 0; j < 16; ++j) {
    float v = acc[j] + b[co0 + j];
    v = v > 0.f ? v : 0.f;
    h2[(((size_t)n * C2 + co0 + j) * H2 + y) * W2 + x] = v;
  }
}

// ---------- enc conv3 (1x1, 32->64) -> z ; also writes z2[row] = sum(z^2) ----------
__global__ __launch_bounds__(256) void k_conv3z(
    const float* __restrict__ h2, const float* __restrict__ w,
    const float* __restrict__ b, float* __restrict__ z,
    float* __restrict__ z2g, int row0)
{
  int bid = blockIdx.x;
  int y = bid & 63, n = bid >> 6;
  __shared__ float sH[C2][64];
  __shared__ float sW[Dd * 33];
  int tid = threadIdx.x;
  for (int i = tid; i < C2 * 64; i += 256) {
    int ci = i >> 6, xx = i & 63;
    sH[ci][xx] = h2[((n * C2 + ci) * H2 + y) * W2 + xx];
  }
  for (int i = tid; i < Dd * C2; i += 256) {
    int d = i >> 5, ci = i & 31;
    sW[d * 33 + ci] = w[i];
  }
  __syncthreads();
  int dg = tid & 3, lx = tid >> 2;
  float acc[16];
#pragma unroll
  for (int j = 0; j < 16; ++j) acc[j] = 0.f;
  for (int ci = 0; ci < C2; ++ci) {
    float u = sH[ci][lx];
#pragma unroll
    for (int j = 0; j < 16; ++j)
      acc[j] += u * sW[(dg * 16 + j) * 33 + ci];
  }
  int row = (n * H2 + y) * W2 + lx;
  float s2 = 0.f;
#pragma unroll
  for (int j = 0; j < 16; ++j) {
    float v = acc[j] + b[dg * 16 + j];
    z[row * Dd + dg * 16 + j] = v;
    s2 = __builtin_fmaf(v, v, s2);
  }
  s2 += __shfl_xor(s2, 1);
  s2 += __shfl_xor(s2, 2);
  if (dg == 0) z2g[row0 + row] = s2;
}

// ---------- VQ main ----------
// v8: revert to the proven round-13 1D form (2D split-phase remap regressed
// 136->150: FETCH dropped 66->46MB proving traffic isn't the limiter).
// One free tweak: z loads hoisted ABOVE the c2s staging block -- the
// __syncthreads barrier blocked compiler motion, so the ~500cy z loads
// used to start only after the barrier; now they overlap c2s + barrier.
__global__ __launch_bounds__(256, 1) void k_vq(
    const float* __restrict__ z, const float* __restrict__ cbf,
    unsigned long long* __restrict__ pk, int row0)
{
  __shared__ float c2s[128];
  int bid = blockIdx.x;
  int sp = bid & 3, rb = bid >> 2;
  int c0 = sp * 128;
  int tid = threadIdx.x;
  // z loads first: no LDS dependence, overlap with c2s staging + barrier
  int r = rb * 256 + tid;
  const float4* zp = (const float4*)(z + (size_t)r * Dd);
  float4 zr[16];
#pragma unroll
  for (int i = 0; i < 16; ++i) zr[i] = zp[i];
  if (tid < 128) {
    const float* cr = cbf + (size_t)(c0 + tid) * Dd;
    float s = 0.f;
#pragma unroll
    for (int d = 0; d < Dd; ++d) { float v = cr[d]; s += v * v; }
    c2s[tid] = s;
  }
  __syncthreads();
  // pin all 64 z components in VGPRs
#pragma unroll
  for (int i = 0; i < 16; i += 4) {
    asm volatile("" : "+v"(zr[i].x), "+v"(zr[i].y), "+v"(zr[i].z), "+v"(zr[i].w),
                      "+v"(zr[i+1].x), "+v"(zr[i+1].y), "+v"(zr[i+1].z), "+v"(zr[i+1].w),
                      "+v"(zr[i+2].x), "+v"(zr[i+2].y), "+v"(zr[i+2].z), "+v"(zr[i+2].w),
                      "+v"(zr[i+3].x), "+v"(zr[i+3].y), "+v"(zr[i+3].z), "+v"(zr[i+3].w));
  }
  float best = 1e30f; int bidx = c0;
#pragma unroll 2
  for (int c = 0; c < 128; ++c) {
    const float4* __restrict__ cr4 = (const float4*)(cbf + (size_t)(c0 + c) * Dd);
    float d0 = 0.f, d1 = 0.f, d2a = 0.f, d3 = 0.f;
#pragma unroll
    for (int i = 0; i < 16; ++i) {
      float4 cv = cr4[i];
      d0 = __builtin_fmaf(zr[i].x, cv.x, d0);
      d1 = __builtin_fmaf(zr[i].y, cv.y, d1);
      d2a = __builtin_fmaf(zr[i].z, cv.z, d2a);
      d3 = __builtin_fmaf(zr[i].w, cv.w, d3);
    }
    float dot = (d0 + d1) + (d2a + d3);
    float dist = c2s[c] - 2.f * dot;
    if (dist < best) { best = dist; bidx = c0 + c; }
  }
  unsigned int u = __float_as_uint(best);
  unsigned int key32 = (u & 0x80000000u) ? ~u : (u | 0x80000000u);
  unsigned long long key =
      ((unsigned long long)key32 << 32) | (unsigned int)bidx;
  atomicMin(&pk[row0 + r], key);
}

// ---------- VQ merge: decode pk key; ||z-c||^2 = dist + ||z||^2 ----------
__global__ __launch_bounds__(256) void k_vqfin(
    const unsigned long long* __restrict__ pk, const float* __restrict__ z2g,
    int* __restrict__ idx, float* __restrict__ lossA, int row0)
{
  int r = blockIdx.x * 256 + threadIdx.x;
  int gi = row0 + r;
  unsigned long long key = pk[gi];
  int bidx = (int)(key & 0xFFFFFFFFull);
  idx[gi] = bidx;
  unsigned int k32 = (unsigned int)(key >> 32);
  unsigned int u = (k32 & 0x80000000u) ? (k32 & 0x7FFFFFFFu) : ~k32;
  float ls = __uint_as_float(u) + z2g[gi];
#pragma unroll
  for (int off = 32; off > 0; off >>= 1) ls += __shfl_down(ls, off);
  if ((threadIdx.x & 63) == 0) atomicAdd(lossA, ls);
}

__global__ void k_loss_final(const float* __restrict__ a, float* __restrict__ out)
{
  if (threadIdx.x == 0) {
    float l = a[0] / (float)(ROWS * Dd);
    out[0] = l;
    out[1] = l;
  }
}

// ---------- d2 interior via G-table gather ----------
// NOTE: writes the FULL tile incl. ring (approximate); k_border_a then
// overwrites the ring with exact values. MUST remain a separate, later
// dispatch (round-15 fusion raced and failed correctness).
__global__ __launch_bounds__(256) void k_upg(
    const int* __restrict__ idx, const float* __restrict__ G,
    const float* __restrict__ bias, float* __restrict__ O, int row0)
{
  int bid = blockIdx.x;
  int tx = bid & 3; bid >>= 2;
  int ty = bid & 3; bid >>= 2;
  int cog = bid & 7; bid >>= 3;
  int n = bid;
  int Y0 = ty * 16, X0 = tx * 16, co0 = cog * 8;
  __shared__ int sIdx[18 * 18];
  int tid = threadIdx.x;
  int base = row0 + (n << 12);
  for (int i = tid; i < 324; i += 256) {
    int r = i / 18, c = i % 18;
    int gy = Y0 - 1 + r; gy = gy < 0 ? 0 : (gy > 63 ? 63 : gy);
    int gx = X0 - 1 + c; gx = gx < 0 ? 0 : (gx > 63 ? 63 : gx);
    sIdx[i] = idx[base + gy * 64 + gx];
  }
  __syncthreads();
  int xx = tid & 15, yy = tid >> 4;
  float4 acc[8];
#pragma unroll
  for (int j = 0; j < 8; ++j) acc[j] = make_float4(0.f, 0.f, 0.f, 0.f);
#pragma unroll
  for (int a = 0; a < 3; ++a)
#pragma unroll
    for (int b = 0; b < 3; ++b) {
      int e = sIdx[(yy + a) * 18 + xx + b];
      const float4* gp =
          (const float4*)(G + ((size_t)(e * 9 + a * 3 + b) * 256) + co0 * 4);
#pragma unroll
      for (int j = 0; j < 8; ++j) {
        float4 gv = gp[j];
        acc[j].x += gv.x; acc[j].y += gv.y;
        acc[j].z += gv.z; acc[j].w += gv.w;
      }
    }
  int oy = 2 * (Y0 + yy), ox = 2 * (X0 + xx);
#pragma unroll
  for (int j = 0; j < 8; ++j) {
    int co = co0 + j;
    float bv = bias[co];
    float2 r0, r1;
    r0.x = acc[j].x + bv; r0.y = acc[j].y + bv;
    r1.x = acc[j].z + bv; r1.y = acc[j].w + bv;
    r0.x = r0.x > 0.f ? r0.x : 0.f; r0.y = r0.y > 0.f ? r0.y : 0.f;
    r1.x = r1.x > 0.f ? r1.x : 0.f; r1.y = r1.y > 0.f ? r1.y : 0.f;
    size_t o = ((size_t)(n * 64 + co) * 128 + oy) * 128 + ox;
    *(float2*)&O[o] = r0;
    *(float2*)&O[o + 128] = r1;
  }
}

// ---------- exact d2 border ring via T1-gathered LDS strips ----------
__global__ __launch_bounds__(256) void k_border_a(
    const int* __restrict__ idx, const float* __restrict__ T1,
    const float* __restrict__ w2, const float* __restrict__ b2,
    float* __restrict__ d2, int row0)
{
  int bid = blockIdx.x;
  int ch = bid & 1; bid >>= 1;
  int side = bid & 3; bid >>= 2;
  int n = bid;
  bool hside = side < 2;
  int rbase = (side == 1) ? 62 : 0;   // d1 rows for h-sides
  int cbase = (side == 3) ? 62 : 0;   // d1 cols for v-sides
  __shared__ int sE[128];
  __shared__ float sD[32 * 128];      // [ci][strip]
  int tid = threadIdx.x;
  if (tid < 128) {
    int yy, xx;
    if (hside) { yy = rbase + (tid >> 6); xx = tid & 63; }
    else       { yy = tid >> 1; xx = cbase + (tid & 1); }
    sE[tid] = idx[row0 + (n << 12) + yy * 64 + xx];
  }
  __syncthreads();
  for (int t = tid; t < 32 * 128; t += 256) {
    int ci = t >> 7, j = t & 127;
    sD[t] = T1[sE[j] * 32 + ci];
  }
  __syncthreads();
  int px = tid & 127, q = tid >> 7;
  int co0 = (ch * 2 + q) * 16;
  int u, v;
  if (side == 0)      { u = 0;   v = px; }
  else if (side == 1) { u = 127; v = px; }
  else if (side == 2) { u = px;  v = 0;   if (px == 0 || px == 127) return; }
  else                { u = px;  v = 127; if (px == 0 || px == 127) return; }
  float acc[16];
#pragma unroll
  for (int j = 0; j < 16; ++j) acc[j] = 0.f;
  for (int ci = 0; ci < 32; ++ci) {
    const float* P = sD + ci * 128;
    float u9[9];
#pragma unroll
    for (int dy = -1; dy <= 1; ++dy)
#pragma unroll
      for (int dx = -1; dx <= 1; ++dx) {
        int uy = u + dy, ux = v + dx;
        float val = 0.f;
        if (uy >= 0 && uy < 128 && ux >= 0 && ux < 128) {
          int ky0, ky1, kx0, kx1; float ay0, ax0;
          if (uy & 1) { ky0 = uy >> 1; ky1 = ky0 + 1; ay0 = .75f; }
          else        { ky1 = uy >> 1; ky0 = ky1 - 1; ay0 = .25f; }
          if (ux & 1) { kx0 = ux >> 1; kx1 = kx0 + 1; ax0 = .75f; }
          else        { kx1 = ux >> 1; kx0 = kx1 - 1; ax0 = .25f; }
          ky0 = ky0 < 0 ? 0 : (ky0 > 63 ? 63 : ky0);
          ky1 = ky1 < 0 ? 0 : (ky1 > 63 ? 63 : ky1);
          kx0 = kx0 < 0 ? 0 : (kx0 > 63 ? 63 : kx0);
          kx1 = kx1 < 0 ? 0 : (kx1 > 63 ? 63 : kx1);
          int i00, i01, i10, i11;
          if (hside) {
            i00 = (ky0 - rbase) * 64 + kx0; i01 = (ky0 - rbase) * 64 + kx1;
            i10 = (ky1 - rbase) * 64 + kx0; i11 = (ky1 - rbase) * 64 + kx1;
          } else {
            i00 = ky0 * 2 + (kx0 - cbase); i01 = ky0 * 2 + (kx1 - cbase);
            i10 = ky1 * 2 + (kx0 - cbase); i11 = ky1 * 2 + (kx1 - cbase);
          }
          float ay1 = 1.f - ay0, ax1 = 1.f - ax0;
          val = ay0 * (ax0 * P[i00] + ax1 * P[i01]) +
                ay1 * (ax0 * P[i10] + ax1 * P[i11]);
        }
        u9[(dy + 1) * 3 + (dx + 1)] = val;
      }
#pragma unroll
    for (int j = 0; j < 16; ++j) {
      const float* wp = w2 + ((size_t)((co0 + j) * 32 + ci)) * 9;
#pragma unroll
      for (int tp = 0; tp < 9; ++tp) acc[j] += u9[tp] * wp[tp];
    }
  }
#pragma unroll
  for (int j = 0; j < 16; ++j) {
    int co = co0 + j;
    float val = acc[j] + b2[co];
    val = val > 0.f ? val : 0.f;
    d2[((size_t)(n * 64 + co) * 128 + u) * 128 + v] = val;
  }
}

// ---------- recon interior: composed conv (LDS weights + T14) ----------
__global__ __launch_bounds__(128) void k_upconv2x_b(
    const float* __restrict__ I, const float* __restrict__ k2t,
    const float* __restrict__ bias, float* __restrict__ O, int n0)
{
  constexpr int Hi = 128, Ci = 64, Co = 3;
  constexpr int NSTG = 4 * 10 * 34;     // 1360 staged input elems/phase
  constexpr int NW = 432;               // staged weight floats/phase
  int bid = blockIdx.x;
  int tx = bid & 3; bid >>= 2;       // 4 x-tiles of 32
  int ty = bid & 15; bid >>= 4;      // 16 y-tiles of 8
  int n = bid;
  int Y0 = ty * 8, X0 = tx * 32;
  __shared__ float sI[4][10 * 35];
  __shared__ __align__(16) float sW[NW];
  int tid = threadIdx.x;
  int lx = tid & 15, ly = tid >> 4;  // 16x8 threads, 2x1 low-res px each

  int soff[11], ldst[11];
#pragma unroll
  for (int k = 0; k < 11; ++k) {
    int i = tid + k * 128;
    if (i < NSTG) {
      int s = i / 340, r2 = i % 340;
      int rr = r2 / 34, cc2 = r2 % 34;
      int gy = Y0 - 1 + rr; gy = gy < 0 ? 0 : (gy > Hi - 1 ? Hi - 1 : gy);
      int gx = X0 - 1 + cc2; gx = gx < 0 ? 0 : (gx > Hi - 1 ? Hi - 1 : gx);
      soff[k] = s * (Hi * Hi) + gy * Hi + gx;
      ldst[k] = s * 350 + rr * 35 + cc2;
    } else {
      soff[k] = -1;
      ldst[k] = 0;
    }
  }
  int wsrc[4];
#pragma unroll
  for (int k = 0; k < 4; ++k) {
    int i = tid + k * 128;
    if (i < NW) {
      int j = i / 144;
      wsrc[k] = i + j * 2160;
    } else {
      wsrc[k] = -1;
    }
  }
  const float* Ibase = I + (size_t)n * Ci * (Hi * Hi);

  float rbuf[11];
#pragma unroll
  for (int k = 0; k < 11; ++k)
    if (soff[k] >= 0) rbuf[k] = Ibase[soff[k]];
  float rw[4];
#pragma unroll
  for (int k = 0; k < 4; ++k)
    if (wsrc[k] >= 0) rw[k] = k2t[wsrc[k]];

  float4 acc[3][2];
#pragma unroll
  for (int j = 0; j < 3; ++j)
#pragma unroll
    for (int py = 0; py < 2; ++py) acc[j][py] = make_float4(0.f, 0.f, 0.f, 0.f);

  for (int c0 = 0; c0 < Ci; c0 += 4) {
    __syncthreads();
#pragma unroll
    for (int k = 0; k < 11; ++k)
      if (soff[k] >= 0) ((float*)sI)[ldst[k]] = rbuf[k];
#pragma unroll
    for (int k = 0; k < 4; ++k)
      if (wsrc[k] >= 0) sW[tid + k * 128] = rw[k];
    __syncthreads();
    if (c0 + 4 < Ci) {
      const float* Inext = Ibase + (size_t)(c0 + 4) * (Hi * Hi);
#pragma unroll
      for (int k = 0; k < 11; ++k)
        if (soff[k] >= 0) rbuf[k] = Inext[soff[k]];
      const float* Wnext = k2t + (size_t)(c0 + 4) * 36;
#pragma unroll
      for (int k = 0; k < 4; ++k)
        if (wsrc[k] >= 0) rw[k] = Wnext[wsrc[k]];
    }
#pragma unroll
    for (int s = 0; s < 4; ++s) {
      float t[3][4];
#pragma unroll
      for (int r = 0; r < 3; ++r)
#pragma unroll
        for (int c = 0; c < 4; ++c)
          t[r][c] = sI[s][(ly + r) * 35 + 2 * lx + c];
#pragma unroll
      for (int j = 0; j < 3; ++j) {
        const float* wj = &sW[(j * 4 + s) * 36];
#pragma unroll
        for (int a = 0; a < 3; ++a)
#pragma unroll
          for (int b = 0; b < 3; ++b) {
            float4 wv = *(const float4*)&wj[(a * 3 + b) * 4];
            float w00 = wv.x;
            float w01 = wv.y;
            float w10 = wv.z;
            float w11 = wv.w;
            float i0 = t[a][b];
            float i1 = t[a][b + 1];
            acc[j][0].x += i0 * w00;
            acc[j][0].y += i0 * w01;
            acc[j][0].z += i1 * w00;
            acc[j][0].w += i1 * w01;
            acc[j][1].x += i0 * w10;
            acc[j][1].y += i0 * w11;
            acc[j][1].z += i1 * w10;
            acc[j][1].w += i1 * w11;
          }
      }
    }
  }
  int ox = 2 * X0 + 4 * lx;
  int oy0 = 2 * (Y0 + ly);
#pragma unroll
  for (int j = 0; j < 3; ++j) {
    float bv = bias[j];
#pragma unroll
    for (int py = 0; py < 2; ++py) {
      float4 v = acc[j][py];
      v.x += bv; v.y += bv; v.z += bv; v.w += bv;
      size_t off = (((size_t)((n0 + n) * Co + j)) * 256 + oy0 + py) * 256 + ox;
      *(float4*)&O[off] = v;
    }
  }
}

// ---------- exact recon border ring via d2-strip LDS ----------
__global__ __launch_bounds__(256) void k_border_b(
    const float* __restrict__ d2, const float* __restrict__ w3,
    const float* __restrict__ b3, float* __restrict__ O, int n0)
{
  int bid = blockIdx.x;
  int side = bid & 3; int n = bid >> 2;
  bool hside = side < 2;
  int rbase = (side == 1) ? 126 : 0;
  int cbase = (side == 3) ? 126 : 0;
  __shared__ float sD[32 * 256];  // [ci][strip]
  int tid = threadIdx.x;
  int px = tid;
  int u, v;
  if (side == 0)      { u = 0;   v = px; }
  else if (side == 1) { u = 255; v = px; }
  else if (side == 2) { u = px;  v = 0; }
  else                { u = px;  v = 255; }
  bool active = hside || (px != 0 && px != 255);
  float a0 = 0.f, a1 = 0.f, a2 = 0.f;
  for (int half = 0; half < 2; ++half) {
    __syncthreads();
    int cib = half * 32;
    for (int t = tid; t < 32 * 256; t += 256) {
      int ci = t >> 8, j = t & 255;
      int yy, xx;
      if (hside) { yy = rbase + (j >> 7); xx = j & 127; }
      else       { yy = j >> 1; xx = cbase + (j & 1); }
      sD[t] = d2[(((size_t)n * 64 + cib + ci) * 128 + yy) * 128 + xx];
    }
    __syncthreads();
    if (active) {
      for (int ci = 0; ci < 32; ++ci) {
        const float* P = sD + ci * 256;
        float u9[9];
#pragma unroll
        for (int dy = -1; dy <= 1; ++dy)
#pragma unroll
          for (int dx = -1; dx <= 1; ++dx) {
            int uy = u + dy, ux = v + dx;
            float val = 0.f;
            if (uy >= 0 && uy < 256 && ux >= 0 && ux < 256) {
              int ky0, ky1, kx0, kx1; float ay0, ax0;
              if (uy & 1) { ky0 = uy >> 1; ky1 = ky0 + 1; ay0 = .75f; }
              else        { ky1 = uy >> 1; ky0 = ky1 - 1; ay0 = .25f; }
              if (ux & 1) { kx0 = ux >> 1; kx1 = kx0 + 1; ax0 = .75f; }
              else        { kx1 = ux >> 1; kx0 = kx1 - 1; ax0 = .25f; }
              ky0 = ky0 < 0 ? 0 : (ky0 > 127 ? 127 : ky0);
              ky1 = ky1 < 0 ? 0 : (ky1 > 127 ? 127 : ky1);
              kx0 = kx0 < 0 ? 0 : (kx0 > 127 ? 127 : kx0);
              kx1 = kx1 < 0 ? 0 : (kx1 > 127 ? 127 : kx1);
              int i00, i01, i10, i11;
              if (hside) {
                i00 = (ky0 - rbase) * 128 + kx0; i01 = (ky0 - rbase) * 128 + kx1;
                i10 = (ky1 - rbase) * 128 + kx0; i11 = (ky1 - rbase) * 128 + kx1;
              } else {
                i00 = ky0 * 2 + (kx0 - cbase); i01 = ky0 * 2 + (kx1 - cbase);
                i10 = ky1 * 2 + (kx0 - cbase); i11 = ky1 * 2 + (kx1 - cbase);
              }
              float ay1 = 1.f - ay0, ax1 = 1.f - ax0;
              val = ay0 * (ax0 * P[i00] + ax1 * P[i01]) +
                    ay1 * (ax0 * P[i10] + ax1 * P[i11]);
            }
            u9[(dy + 1) * 3 + (dx + 1)] = val;
          }
        const float* w0 = w3 + ((size_t)(0 * 64 + cib + ci)) * 9;
        const float* w1 = w3 + ((size_t)(1 * 64 + cib + ci)) * 9;
        const float* w2p = w3 + ((size_t)(2 * 64 + cib + ci)) * 9;
#pragma unroll
        for (int tp = 0; tp < 9; ++tp) {
          a0 += u9[tp] * w0[tp];
          a1 += u9[tp] * w1[tp];
          a2 += u9[tp] * w2p[tp];
        }
      }
    }
  }
  if (active) {
    size_t b = ((size_t)(n0 + n) * 3) * 65536 + (size_t)u * 256 + v;
    O[b] = a0 + b3[0];
    O[b + 65536] = a1 + b3[1];
    O[b + 131072] = a2 + b3[2];
  }
}

extern "C" void kernel_launch(void* const* d_in, const int* in_sizes, int n_in,
                              void* d_out, int out_size, void* d_ws, size_t ws_size,
                              hipStream_t stream)
{
  const float* x      = (const float*)d_in[0];
  const float* cb     = (const float*)d_in[1];
  const float* enc_w1 = (const float*)d_in[2];
  const float* enc_b1 = (const float*)d_in[3];
  const float* enc_w2 = (const float*)d_in[4];
  const float* enc_b2 = (const float*)d_in[5];
  const float* enc_w3 = (const float*)d_in[6];
  const float* enc_b3 = (const float*)d_in[7];
  const float* dec_w1 = (const float*)d_in[8];
  const float* dec_b1 = (const float*)d_in[9];
  const float* dec_w2 = (const float*)d_in[10];
  const float* dec_b2 = (const float*)d_in[11];
  const float* dec_w3 = (const float*)d_in[12];
  const float* dec_b3 = (const float*)d_in[13];

  float* ws = (float*)d_ws;
  float* lossA = ws;
  int* idx = (int*)(lossA + 64);
  unsigned long long* pk = (unsigned long long*)(idx + ROWS);
  float* z2g = (float*)(pk + ROWS);
  float* k2a = z2g + ROWS;
  float* k2b = k2a + K2A_FLOATS;   // k2t layout for upconv
  float* T1  = k2b + K2B_FLOATS;
  float* G   = T1 + T1_FLOATS;
  float* wT2 = G + G_FLOATS + 64;
  float* chunkbuf = wT2 + WT2_FLOATS;

  int CH = 1;
  for (int c = 32; c >= 1; c >>= 1) {
    size_t need = ((size_t)FIX_FLOATS + (size_t)(H1_PER_N + Z_PER_N + H2_PER_N) * c) * 4;
    if (need <= ws_size) { CH = c; break; }
  }
  float* h1 = chunkbuf;                   // NHWC for encoder; d2 buffer for decoder
  float* z  = h1 + (size_t)H1_PER_N * CH;
  float* h2 = z + (size_t)Z_PER_N * CH;

  // fused setup: init | wtrans | wtransq | wt2 | gtab1 (657 blocks)
  k_setup<<<657, 256, 0, stream>>>(lossA, pk, dec_w2, k2a, dec_w3, k2b,
                                   enc_w2, wT2, cb, dec_w1, dec_b1, T1);
  k_gtab2<<<Kc, 256, 0, stream>>>(k2a, T1, G);

  float* out = (float*)d_out;

  for (int n0 = 0; n0 < Bn; n0 += CH) {
    int row0 = n0 * H2 * W2;
    k_conv1<<<CH * 128, 256, 0, stream>>>(x, enc_w1, enc_b1, h1, n0);
    k_conv2<<<CH * 32, 256, 0, stream>>>(h1, wT2, enc_b2, h2);
    k_conv3z<<<CH * 64, 256, 0, stream>>>(h2, enc_w3, enc_b3, z, z2g, row0);
    k_vq<<<CH * 16 * 4, 256, 0, stream>>>(z, cb, pk, row0);
    k_vqfin<<<CH * 16, 256, 0, stream>>>(pk, z2g, idx, lossA, row0);
    // d2 interior (composed) then exact ring -- ORDER REQUIRED (ring overwrite)
    k_upg<<<CH * 8 * 16, 256, 0, stream>>>(idx, G, dec_b2, h1, row0);
    k_border_a<<<CH * 4 * 2, 256, 0, stream>>>(idx, T1, dec_w2, dec_b2, h1, row0);
    // recon interior (composed) then exact ring
    k_upconv2x_b<<<CH * 64, 128, 0, stream>>>(h1, k2b, dec_b3, out + 2, n0);
    k_border_b<<<CH * 4, 256, 0, stream>>>(h1, dec_w3, dec_b3, out + 2, n0);
  }
  k_loss_final<<<1, 64, 0, stream>>>(lossA, out);
}